// Round 1
// baseline (177.191 us; speedup 1.0000x reference)
//
#include <hip/hip_runtime.h>
#include <stdint.h>

// Problem constants
#define SCALE 0.125f   // 1/sqrt(64)

typedef short s16x8 __attribute__((ext_vector_type(8)));
typedef float f32x4 __attribute__((ext_vector_type(4)));

__device__ __forceinline__ unsigned short f2bf(float x){
  union { float f; unsigned int u; } v; v.f = x;
  unsigned int r = v.u + 0x7fffu + ((v.u >> 16) & 1u);
  return (unsigned short)(r >> 16);
}
__device__ __forceinline__ float bf2f(unsigned short u){
  union { unsigned int u; float f; } v; v.u = ((unsigned int)u) << 16;
  return v.f;
}
__device__ __forceinline__ f32x4 mfma16(s16x8 a, s16x8 b, f32x4 c){
  return __builtin_amdgcn_mfma_f32_16x16x32_bf16(a, b, c, 0, 0, 0);
}
__device__ __forceinline__ void gld_lds16(const void* g, void* l){
  __builtin_amdgcn_global_load_lds(
      (const __attribute__((address_space(1))) unsigned int*)g,
      (__attribute__((address_space(3))) unsigned int*)l, 16, 0, 0);
}

// ---------------- cast q fp32 -> bf16 (4M elems, 8/thread) ----------------
__global__ __launch_bounds__(256) void cast_kernel(const float* __restrict__ in,
                                                   unsigned short* __restrict__ out){
  int i = blockIdx.x*256 + threadIdx.x;
  const float4* p = (const float4*)in + (size_t)i*2;
  float4 a = p[0], b = p[1];
  unsigned short t[8] = {f2bf(a.x),f2bf(a.y),f2bf(a.z),f2bf(a.w),
                         f2bf(b.x),f2bf(b.y),f2bf(b.z),f2bf(b.w)};
  *(s16x8*)(out + (size_t)i*8) = *(const s16x8*)t;
}

// ---------------- W fp32 [K][N] -> bf16 Wt [N][K] (B^T form) ----------------
__global__ __launch_bounds__(256) void wtrans_kernel(const float* __restrict__ W0,
    const float* __restrict__ W1, const float* __restrict__ W2, const float* __restrict__ W3,
    unsigned short* __restrict__ Wt){
  const float* src = (blockIdx.z==0)?W0:(blockIdx.z==1)?W1:(blockIdx.z==2)?W2:W3;
  unsigned short* dst = Wt + (size_t)blockIdx.z*1048576;
  int k0 = blockIdx.x*64, n0 = blockIdx.y*64;
  __shared__ unsigned short tile[64*72];
  int tid = threadIdx.x;
  int r = tid>>2, c = (tid&3)*16;
  const float* p = src + (size_t)(k0+r)*1024 + n0 + c;
  #pragma unroll
  for (int j=0;j<16;j++) tile[r*72 + c + j] = f2bf(p[j]);
  __syncthreads();
  int n = tid>>2, kc = (tid&3)*16;
  unsigned short o[16];
  #pragma unroll
  for (int j=0;j<16;j++) o[j] = tile[(kc+j)*72 + n];
  *(s16x8*)&dst[(size_t)(n0+n)*1024 + k0 + kc]     = *(const s16x8*)o;
  *(s16x8*)&dst[(size_t)(n0+n)*1024 + k0 + kc + 8] = *(const s16x8*)(o+8);
}

// ---------------- 128x128 bf16 GEMM, Bt in [N][K] form ----------------
// MODE 0: store fp32 to outF [4096][1024]
// MODE 1: store bf16 heads layout [b,h,s,d] to outH + z*4M; Bt offset by z*1M
template<int MODE>
__global__ __launch_bounds__(256) void gemm128(const unsigned short* __restrict__ A,
    const unsigned short* __restrict__ Bt, unsigned short* __restrict__ outH,
    float* __restrict__ outF){
  __shared__ unsigned short As[128*32];
  __shared__ unsigned short Bs[128*32];
  int tid = threadIdx.x;
  int w = tid>>6, l = tid&63;
  int wr = w>>1, wc = w&1;
  int m0 = blockIdx.x*128, n0 = blockIdx.y*128;
  const unsigned short* Bz = Bt + (size_t)blockIdx.z*1048576;
  f32x4 acc[4][4];
  #pragma unroll
  for (int r=0;r<4;r++)
    #pragma unroll
    for (int c=0;c<4;c++){ f32x4 z = {0.f,0.f,0.f,0.f}; acc[r][c] = z; }
  int srow = tid>>2, scol = (tid&3)*8;
  const unsigned short* ga0 = A  + (size_t)(m0 + srow)*1024 + scol;
  const unsigned short* ga1 = A  + (size_t)(m0 + 64 + srow)*1024 + scol;
  const unsigned short* gb0 = Bz + (size_t)(n0 + srow)*1024 + scol;
  const unsigned short* gb1 = Bz + (size_t)(n0 + 64 + srow)*1024 + scol;
  unsigned short* lA = As + w*512;  // wave-uniform base; HW writes lane*16B
  unsigned short* lB = Bs + w*512;
  for (int k0=0;k0<1024;k0+=32){
    gld_lds16(ga0 + k0, lA);
    gld_lds16(ga1 + k0, lA + 2048);
    gld_lds16(gb0 + k0, lB);
    gld_lds16(gb1 + k0, lB + 2048);
    __syncthreads();
    s16x8 af[4], bfr[4];
    #pragma unroll
    for (int r=0;r<4;r++) af[r]  = *(const s16x8*)&As[(wr*64 + r*16 + (l&15))*32 + (l>>4)*8];
    #pragma unroll
    for (int c=0;c<4;c++) bfr[c] = *(const s16x8*)&Bs[(wc*64 + c*16 + (l&15))*32 + (l>>4)*8];
    #pragma unroll
    for (int r=0;r<4;r++)
      #pragma unroll
      for (int c=0;c<4;c++)
        acc[r][c] = mfma16(af[r], bfr[c], acc[r][c]);
    __syncthreads();
  }
  #pragma unroll
  for (int r=0;r<4;r++){
    #pragma unroll
    for (int c=0;c<4;c++){
      #pragma unroll
      for (int i=0;i<4;i++){
        int m = m0 + wr*64 + r*16 + ((l>>4)<<2) + i;
        int n = n0 + wc*64 + c*16 + (l&15);
        if constexpr (MODE==0){
          outF[(size_t)m*1024 + n] = acc[r][c][i];
        } else {
          int bq = m >> 11, sq = m & 2047;
          int hq = n >> 6,  dq = n & 63;
          unsigned short* oz = outH + (size_t)blockIdx.z*4194304;
          oz[(((size_t)(bq*16 + hq))*2048 + sq)*64 + dq] = f2bf(acc[r][c][i]);
        }
      }
    }
  }
}

// ---------------- V [bh][2048][64] -> Vt [bh][64][2048] ----------------
__global__ __launch_bounds__(256) void vtrans_kernel(const unsigned short* __restrict__ Vh,
    unsigned short* __restrict__ VtG){
  int bh = blockIdx.y, t0 = blockIdx.x*64;
  __shared__ unsigned short tile[64*72];
  int tid = threadIdx.x;
  #pragma unroll
  for (int p=0;p<2;p++){
    int idx = p*2048 + tid*8;
    int r = idx>>6, c = idx&63;
    *(s16x8*)&tile[r*72 + c] = *(const s16x8*)&Vh[((size_t)bh*2048 + t0 + r)*64 + c];
  }
  __syncthreads();
  #pragma unroll
  for (int p=0;p<2;p++){
    int idx = p*2048 + tid*8;
    int d = idx>>6, c = idx&63;
    unsigned short o[8];
    #pragma unroll
    for (int j=0;j<8;j++) o[j] = tile[(c+j)*72 + d];
    *(s16x8*)&VtG[((size_t)bh*64 + d)*2048 + t0 + c] = *(const s16x8*)o;
  }
}

// ---------------- row norms of bf16 [rows][64] -> fp32 ----------------
__global__ __launch_bounds__(256) void norms_kernel(const unsigned short* __restrict__ Qh,
    const unsigned short* __restrict__ Kh, float* __restrict__ qn, float* __restrict__ kn){
  const unsigned short* src = blockIdx.y ? Kh : Qh;
  float* dst = blockIdx.y ? kn : qn;
  int row = blockIdx.x*64 + (threadIdx.x>>2);
  int seg = threadIdx.x & 3;
  const unsigned short* p = src + (size_t)row*64 + seg*16;
  float s = 0.f;
  #pragma unroll
  for (int ch=0;ch<2;ch++){
    s16x8 v = *(const s16x8*)(p + ch*8);
    #pragma unroll
    for (int j=0;j<8;j++){ float f = bf2f((unsigned short)v[j]); s += f*f; }
  }
  s += __shfl_xor(s, 1);
  s += __shfl_xor(s, 2);
  if (seg==0) dst[row] = s;
}

// ---------------- attention: out[s] = sum_{t>s} exp(-g*SCALE*dist) * v[t] ----------------
__global__ __launch_bounds__(256) void attn_kernel(const unsigned short* __restrict__ Qh,
    const unsigned short* __restrict__ Kh, const unsigned short* __restrict__ VtG,
    const float* __restrict__ qn, const float* __restrict__ kn,
    const float* __restrict__ gamma, unsigned short* __restrict__ attnO){
  int bh = blockIdx.y; int b = bh>>4, h = bh&15;
  int s0 = blockIdx.x*64;
  int tid = threadIdx.x, w = tid>>6, l = tid&63;
  float gs = gamma[h]*SCALE;
  __shared__ unsigned short Ks[64*72];
  __shared__ unsigned short Vs[64*72];
  __shared__ unsigned short Ps[4][16*72];
  __shared__ float knl[64];

  int qrow = s0 + w*16 + (l&15);
  const unsigned short* qbase = Qh + ((size_t)bh*2048 + qrow)*64;
  s16x8 qf0 = *(const s16x8*)(qbase + (l>>4)*8);
  s16x8 qf1 = *(const s16x8*)(qbase + 32 + (l>>4)*8);
  int srow = s0 + w*16 + (l>>4)*4;
  float qnr[4];
  #pragma unroll
  for (int i=0;i<4;i++) qnr[i] = qn[bh*2048 + srow + i];

  f32x4 accO[4];
  #pragma unroll
  for (int cd=0;cd<4;cd++){ f32x4 z = {0.f,0.f,0.f,0.f}; accO[cd] = z; }

  for (int t0 = s0; t0 < 2048; t0 += 64){
    #pragma unroll
    for (int p=0;p<2;p++){
      int idx = p*2048 + tid*8;
      int r = idx>>6, c = idx&63;
      *(s16x8*)&Ks[r*72 + c] = *(const s16x8*)&Kh[((size_t)bh*2048 + t0 + r)*64 + c];
      *(s16x8*)&Vs[r*72 + c] = *(const s16x8*)&VtG[((size_t)bh*64 + r)*2048 + t0 + c];
    }
    if (tid < 64) knl[tid] = kn[bh*2048 + t0 + tid];
    __syncthreads();

    #pragma unroll
    for (int c=0;c<4;c++){
      s16x8 kb0 = *(const s16x8*)&Ks[(c*16 + (l&15))*72 + (l>>4)*8];
      s16x8 kb1 = *(const s16x8*)&Ks[(c*16 + (l&15))*72 + 32 + (l>>4)*8];
      f32x4 sc = {0.f,0.f,0.f,0.f};
      sc = mfma16(qf0, kb0, sc);
      sc = mfma16(qf1, kb1, sc);
      float knv = knl[c*16 + (l&15)];
      int t = t0 + c*16 + (l&15);
      #pragma unroll
      for (int i=0;i<4;i++){
        int si = srow + i;
        float pv = 0.f;
        if (t > si){
          float dist = fmaxf(qnr[i] - 2.f*sc[i] + knv, 0.f);
          pv = __expf(-gs*dist);
        }
        Ps[w][((l>>4)*4 + i)*72 + c*16 + (l&15)] = f2bf(pv);
      }
    }
    // P (wave-private) -> A-fragments, then PV
    s16x8 pa0 = *(const s16x8*)&Ps[w][(l&15)*72 + (l>>4)*8];
    s16x8 pa1 = *(const s16x8*)&Ps[w][(l&15)*72 + 32 + (l>>4)*8];
    #pragma unroll
    for (int cd=0;cd<4;cd++){
      s16x8 v0 = *(const s16x8*)&Vs[(cd*16 + (l&15))*72 + (l>>4)*8];
      s16x8 v1 = *(const s16x8*)&Vs[(cd*16 + (l&15))*72 + 32 + (l>>4)*8];
      accO[cd] = mfma16(pa0, v0, accO[cd]);
      accO[cd] = mfma16(pa1, v1, accO[cd]);
    }
    __syncthreads();
  }
  #pragma unroll
  for (int cd=0;cd<4;cd++){
    #pragma unroll
    for (int i=0;i<4;i++){
      int s = srow + i;
      int d = cd*16 + (l&15);
      attnO[((size_t)b*2048 + s)*1024 + h*64 + d] = f2bf(accO[cd][i]);
    }
  }
}

extern "C" void kernel_launch(void* const* d_in, const int* in_sizes, int n_in,
                              void* d_out, int out_size, void* d_ws, size_t ws_size,
                              hipStream_t stream){
  const float* q  = (const float*)d_in[0];
  const float* Wq = (const float*)d_in[1];
  const float* Wk = (const float*)d_in[2];
  const float* Wv = (const float*)d_in[3];
  const float* Wo = (const float*)d_in[4];
  const float* gm = (const float*)d_in[5];
  float* out = (float*)d_out;

  // workspace layout (all 16B aligned); total ~56.5 MB
  unsigned short* qbf = (unsigned short*)d_ws;  // 4096x1024 bf16
  unsigned short* Wt  = qbf + 4194304;          // 4 x [1024][1024] bf16 (B^T form)
  unsigned short* Qh  = Wt  + 4194304;          // [bh][2048][64]
  unsigned short* Kh  = Qh  + 4194304;
  unsigned short* Vh  = Kh  + 4194304;
  unsigned short* Vt  = Vh  + 4194304;          // [bh][64][2048]
  unsigned short* aO  = Vt  + 4194304;          // [4096][1024] bf16
  float* qn = (float*)(aO + 4194304);           // [bh*2048]
  float* kn = qn + 65536;

  cast_kernel  <<<2048, 256, 0, stream>>>(q, qbf);
  wtrans_kernel<<<dim3(16,16,4), 256, 0, stream>>>(Wq, Wk, Wv, Wo, Wt);
  gemm128<1>   <<<dim3(32,8,3), 256, 0, stream>>>(qbf, Wt, Qh, nullptr);
  vtrans_kernel<<<dim3(32,32), 256, 0, stream>>>(Vh, Vt);
  norms_kernel <<<dim3(1024,2), 256, 0, stream>>>(Qh, Kh, qn, kn);
  attn_kernel  <<<dim3(32,32), 256, 0, stream>>>(Qh, Kh, Vt, qn, kn, gm, aO);
  gemm128<0>   <<<dim3(32,8,1), 256, 0, stream>>>(aO, Wt + 3*1048576, nullptr, out);
}

// Round 2
// 144.186 us; speedup vs baseline: 1.2289x; 1.2289x over previous
//
#include <hip/hip_runtime.h>
#include <stdint.h>

#define SCALE 0.125f   // 1/sqrt(64)

typedef short s16x8 __attribute__((ext_vector_type(8)));
typedef float f32x4 __attribute__((ext_vector_type(4)));

__device__ __forceinline__ unsigned short f2bf(float x){
  union { float f; unsigned int u; } v; v.f = x;
  unsigned int r = v.u + 0x7fffu + ((v.u >> 16) & 1u);
  return (unsigned short)(r >> 16);
}
__device__ __forceinline__ float bf2f(unsigned short u){
  union { unsigned int u; float f; } v; v.u = ((unsigned int)u) << 16;
  return v.f;
}
__device__ __forceinline__ f32x4 mfma16(s16x8 a, s16x8 b, f32x4 c){
  return __builtin_amdgcn_mfma_f32_16x16x32_bf16(a, b, c, 0, 0, 0);
}
__device__ __forceinline__ void gld_lds16(const void* g, void* l){
  __builtin_amdgcn_global_load_lds(
      (const __attribute__((address_space(1))) unsigned int*)g,
      (__attribute__((address_space(3))) unsigned int*)l, 16, 0, 0);
}
// pack two f32 -> two bf16 in one u32 (RNE, matches f2bf)
__device__ __forceinline__ unsigned int cvtpk(float lo, float hi){
  unsigned int r;
  asm("v_cvt_pk_bf16_f32 %0, %1, %2" : "=v"(r) : "v"(lo), "v"(hi));
  return r;
}

// ---------------- cast q fp32 -> bf16 (4M elems, 8/thread) ----------------
__global__ __launch_bounds__(256) void cast_kernel(const float* __restrict__ in,
                                                   unsigned short* __restrict__ out){
  int i = blockIdx.x*256 + threadIdx.x;
  const float4* p = (const float4*)in + (size_t)i*2;
  float4 a = p[0], b = p[1];
  unsigned short t[8] = {f2bf(a.x),f2bf(a.y),f2bf(a.z),f2bf(a.w),
                         f2bf(b.x),f2bf(b.y),f2bf(b.z),f2bf(b.w)};
  *(s16x8*)(out + (size_t)i*8) = *(const s16x8*)t;
}

// ---------------- W fp32 [K][N] -> bf16 Wt [N][K] (B^T form) ----------------
__global__ __launch_bounds__(256) void wtrans_kernel(const float* __restrict__ W0,
    const float* __restrict__ W1, const float* __restrict__ W2, const float* __restrict__ W3,
    unsigned short* __restrict__ Wt){
  const float* src = (blockIdx.z==0)?W0:(blockIdx.z==1)?W1:(blockIdx.z==2)?W2:W3;
  unsigned short* dst = Wt + (size_t)blockIdx.z*1048576;
  int k0 = blockIdx.x*64, n0 = blockIdx.y*64;
  __shared__ unsigned short tile[64*72];
  int tid = threadIdx.x;
  int r = tid>>2, c = (tid&3)*16;
  const float* p = src + (size_t)(k0+r)*1024 + n0 + c;
  #pragma unroll
  for (int j=0;j<16;j++) tile[r*72 + c + j] = f2bf(p[j]);
  __syncthreads();
  int n = tid>>2, kc = (tid&3)*16;
  unsigned short o[16];
  #pragma unroll
  for (int j=0;j<16;j++) o[j] = tile[(kc+j)*72 + n];
  *(s16x8*)&dst[(size_t)(n0+n)*1024 + k0 + kc]     = *(const s16x8*)o;
  *(s16x8*)&dst[(size_t)(n0+n)*1024 + k0 + kc + 8] = *(const s16x8*)(o+8);
}

// ---------------- 128x128 bf16 GEMM, Bt in [N][K] form ----------------
// MODE 0: store fp32 to outF [4096][1024]
// MODE 1: z=0/1 -> heads layout [bh][s][d] bf16 + fused row-norms (qn/kn);
//         z=2 -> transposed V directly into Vt [bh][64][2048]
template<int MODE>
__global__ __launch_bounds__(256) void gemm128(const unsigned short* __restrict__ A,
    const unsigned short* __restrict__ Bt, unsigned short* __restrict__ outH,
    float* __restrict__ outF, unsigned short* __restrict__ VtG,
    float* __restrict__ qn, float* __restrict__ kn){
  __shared__ unsigned short As[128*32];
  __shared__ unsigned short Bs[128*32];
  int tid = threadIdx.x;
  int w = tid>>6, l = tid&63;
  int wr = w>>1, wc = w&1;
  int m0 = blockIdx.x*128, n0 = blockIdx.y*128;
  const unsigned short* Bz = Bt + (size_t)blockIdx.z*1048576;
  f32x4 acc[4][4];
  #pragma unroll
  for (int r=0;r<4;r++)
    #pragma unroll
    for (int c=0;c<4;c++){ f32x4 z = {0.f,0.f,0.f,0.f}; acc[r][c] = z; }
  int srow = tid>>2, scol = (tid&3)*8;
  const unsigned short* ga0 = A  + (size_t)(m0 + srow)*1024 + scol;
  const unsigned short* ga1 = A  + (size_t)(m0 + 64 + srow)*1024 + scol;
  const unsigned short* gb0 = Bz + (size_t)(n0 + srow)*1024 + scol;
  const unsigned short* gb1 = Bz + (size_t)(n0 + 64 + srow)*1024 + scol;
  unsigned short* lA = As + w*512;
  unsigned short* lB = Bs + w*512;
  for (int k0=0;k0<1024;k0+=32){
    gld_lds16(ga0 + k0, lA);
    gld_lds16(ga1 + k0, lA + 2048);
    gld_lds16(gb0 + k0, lB);
    gld_lds16(gb1 + k0, lB + 2048);
    __syncthreads();
    s16x8 af[4], bfr[4];
    #pragma unroll
    for (int r=0;r<4;r++) af[r]  = *(const s16x8*)&As[(wr*64 + r*16 + (l&15))*32 + (l>>4)*8];
    #pragma unroll
    for (int c=0;c<4;c++) bfr[c] = *(const s16x8*)&Bs[(wc*64 + c*16 + (l&15))*32 + (l>>4)*8];
    #pragma unroll
    for (int r=0;r<4;r++)
      #pragma unroll
      for (int c=0;c<4;c++)
        acc[r][c] = mfma16(af[r], bfr[c], acc[r][c]);
    __syncthreads();
  }
  if constexpr (MODE==0){
    #pragma unroll
    for (int r=0;r<4;r++)
      #pragma unroll
      for (int c=0;c<4;c++)
        #pragma unroll
        for (int i=0;i<4;i++){
          int m = m0 + wr*64 + r*16 + ((l>>4)<<2) + i;
          int n = n0 + wc*64 + c*16 + (l&15);
          outF[(size_t)m*1024 + n] = acc[r][c][i];
        }
  } else {
    int z = blockIdx.z;
    unsigned short* oz = outH + (size_t)z*4194304;
    #pragma unroll
    for (int r=0;r<4;r++){
      #pragma unroll
      for (int i=0;i<4;i++){
        int m = m0 + wr*64 + r*16 + ((l>>4)<<2) + i;
        int bq = m >> 11, sq = m & 2047;
        float nrm = 0.f;
        #pragma unroll
        for (int c=0;c<4;c++){
          int n = n0 + wc*64 + c*16 + (l&15);
          int hq = n >> 6, dq = n & 63;
          int bh = bq*16 + hq;
          unsigned short bv = f2bf(acc[r][c][i]);
          if (z == 2) VtG[((size_t)bh*64 + dq)*2048 + sq] = bv;
          else        oz[((size_t)bh*2048 + sq)*64 + dq] = bv;
          float vf = bf2f(bv);
          nrm = fmaf(vf, vf, nrm);
        }
        if (z < 2){
          nrm += __shfl_xor(nrm, 1);
          nrm += __shfl_xor(nrm, 2);
          nrm += __shfl_xor(nrm, 4);
          nrm += __shfl_xor(nrm, 8);
          if ((l&15) == 0){
            int hq = (n0 + wc*64) >> 6;
            float* dst = z ? kn : qn;
            dst[(size_t)(bq*16 + hq)*2048 + sq] = nrm;
          }
        }
      }
    }
  }
}

// ---------------- attention ----------------
// out[s] = sum_{t>s} exp(-g*SCALE*max(qn[s]-2*q.k+kn[t],0)) * v[t]
// swapped QK (S^T = K x Q), P stored [m][t] per-wave, 2-phase dbuf staging,
// XOR-swizzled LDS (linear gld_lds dest + pre-swizzled global source).
__global__ __launch_bounds__(256) void attn_kernel(const unsigned short* __restrict__ Qh,
    const unsigned short* __restrict__ Kh, const unsigned short* __restrict__ VtG,
    const float* __restrict__ qn, const float* __restrict__ kn,
    const float* __restrict__ gamma, unsigned short* __restrict__ attnO){
  __shared__ short Ks[2][4096];   // [t 64][d 64], chunk-swizzled
  __shared__ short Vs[2][4096];   // [d 64][t 64], chunk-swizzled
  __shared__ short Ps[4][1024];   // per-wave P [m 16][t 64], swizzled

  int bid = blockIdx.x;
  int bh = bid & 31; int b = bh>>4, h = bh&15;
  int rr = bid >> 5;
  int si = (rr&1) ? (31 - (rr>>1)) : (rr>>1);   // heavy/light pairing
  int s0 = si*64;
  int tid = threadIdx.x, w = tid>>6, l = tid&63;
  int lm = l & 15, hi = l >> 4;
  float gs = gamma[h]*SCALE;
  float gs2 = 2.f*gs;

  int sq = s0 + w*16 + lm;
  const unsigned short* qbase = Qh + ((size_t)bh*2048 + sq)*64;
  s16x8 qf0 = *(const s16x8*)(qbase + hi*8);
  s16x8 qf1 = *(const s16x8*)(qbase + 32 + hi*8);
  float qn_r = qn[(size_t)bh*2048 + sq];
  float gq = -gs*qn_r;
  const float* knp = kn + (size_t)bh*2048;

  // staging: thread stages 16B chunks; LDS row = p*32 + w*8 + (l>>3), chunk = l&7
  // source chunk pre-swizzled: chunk ^ (row&7), row&7 == (l>>3)
  int chs = ((l&7) ^ (l>>3))*8;
  const unsigned short* kp0 = Kh  + ((size_t)bh*2048 + s0 + w*8 + (l>>3))*64 + chs;
  const unsigned short* vp0 = VtG + ((size_t)bh*64 + w*8 + (l>>3))*2048 + s0 + chs;

  f32x4 accO[4];
  #pragma unroll
  for (int df=0; df<4; df++){ f32x4 zz = {0.f,0.f,0.f,0.f}; accO[df] = zz; }

  // prologue: stage tile 0 into buf 0
  gld_lds16(kp0,           &Ks[0][w*512]);
  gld_lds16(kp0 + 32*64,   &Ks[0][w*512 + 2048]);
  gld_lds16(vp0,           &Vs[0][w*512]);
  gld_lds16(vp0 + 32*2048, &Vs[0][w*512 + 2048]);
  __syncthreads();

  int swl = (lm & 7) << 4;   // read-side swizzle (bytes, same involution)
  int cur = 0;
  for (int t0 = s0; t0 < 2048; t0 += 64, cur ^= 1){
    int nxt = t0 + 64;
    if (nxt < 2048){
      int dt = nxt - s0;
      const unsigned short* kp = kp0 + (size_t)dt*64;
      const unsigned short* vp = vp0 + dt;
      gld_lds16(kp,           &Ks[cur^1][w*512]);
      gld_lds16(kp + 32*64,   &Ks[cur^1][w*512 + 2048]);
      gld_lds16(vp,           &Vs[cur^1][w*512]);
      gld_lds16(vp + 32*2048, &Vs[cur^1][w*512 + 2048]);
    }
    const char* kbase = (const char*)&Ks[cur][0];
    const char* vbase = (const char*)&Vs[cur][0];
    char* pbase = (char*)&Ps[w][0];

    // QK^T swapped: S^T[t][m], lane: m = lm (own row), t = t0+tf*16+hi*4+i
    #pragma unroll
    for (int tf=0; tf<4; tf++){
      int ro = (tf*16 + lm)*128;
      s16x8 ka = *(const s16x8*)(kbase + ro + ((hi*16) ^ swl));
      s16x8 kb = *(const s16x8*)(kbase + ro + ((64 + hi*16) ^ swl));
      f32x4 sc = {0.f,0.f,0.f,0.f};
      sc = mfma16(ka, qf0, sc);
      sc = mfma16(kb, qf1, sc);
      float4 knv = *(const float4*)(knp + t0 + tf*16 + hi*4);
      float p0, p1, p2, p3;
      {
        int tbase = t0 + tf*16 + hi*4;
        float a0 = fminf(fmaf(gs2, sc[0], fmaf(-gs, knv.x, gq)), 0.f);
        float a1 = fminf(fmaf(gs2, sc[1], fmaf(-gs, knv.y, gq)), 0.f);
        float a2 = fminf(fmaf(gs2, sc[2], fmaf(-gs, knv.z, gq)), 0.f);
        float a3 = fminf(fmaf(gs2, sc[3], fmaf(-gs, knv.w, gq)), 0.f);
        p0 = (tbase + 0 > sq) ? __expf(a0) : 0.f;
        p1 = (tbase + 1 > sq) ? __expf(a1) : 0.f;
        p2 = (tbase + 2 > sq) ? __expf(a2) : 0.f;
        p3 = (tbase + 3 > sq) ? __expf(a3) : 0.f;
      }
      unsigned int pk0 = cvtpk(p0, p1);
      unsigned int pk1 = cvtpk(p2, p3);
      int po = lm*128 + (((tf*32 + hi*8) ^ swl));
      *(unsigned int*)(pbase + po)     = pk0;
      *(unsigned int*)(pbase + po + 4) = pk1;
    }

    // PV: out[m][d] = P[m][t] * V[t][d]; A = P (rows m=lm), B = V^T rows from Vs[d][t]
    #pragma unroll
    for (int kf=0; kf<2; kf++){
      s16x8 pa = *(const s16x8*)(pbase + lm*128 + ((kf*64 + hi*16) ^ swl));
      #pragma unroll
      for (int df=0; df<4; df++){
        int vo = (df*16 + lm)*128 + ((kf*64 + hi*16) ^ swl);
        s16x8 vb = *(const s16x8*)(vbase + vo);
        accO[df] = mfma16(pa, vb, accO[df]);
      }
    }
    __syncthreads();
  }

  #pragma unroll
  for (int df=0; df<4; df++)
    #pragma unroll
    for (int i=0; i<4; i++){
      int s = s0 + w*16 + hi*4 + i;
      attnO[((size_t)b*2048 + s)*1024 + h*64 + df*16 + lm] = f2bf(accO[df][i]);
    }
}

extern "C" void kernel_launch(void* const* d_in, const int* in_sizes, int n_in,
                              void* d_out, int out_size, void* d_ws, size_t ws_size,
                              hipStream_t stream){
  const float* q  = (const float*)d_in[0];
  const float* Wq = (const float*)d_in[1];
  const float* Wk = (const float*)d_in[2];
  const float* Wv = (const float*)d_in[3];
  const float* Wo = (const float*)d_in[4];
  const float* gm = (const float*)d_in[5];
  float* out = (float*)d_out;

  unsigned short* qbf = (unsigned short*)d_ws;  // 4096x1024 bf16
  unsigned short* Wt  = qbf + 4194304;          // 4 x [1024][1024] bf16 (B^T form)
  unsigned short* Qh  = Wt  + 4194304;          // [bh][2048][64]
  unsigned short* Kh  = Qh  + 4194304;
  unsigned short* Vh  = Kh  + 4194304;          // (unused slot, kept for layout)
  unsigned short* Vt  = Vh  + 4194304;          // [bh][64][2048]
  unsigned short* aO  = Vt  + 4194304;          // [4096][1024] bf16
  float* qn = (float*)(aO + 4194304);           // [bh*2048]
  float* kn = qn + 65536;

  cast_kernel  <<<2048, 256, 0, stream>>>(q, qbf);
  wtrans_kernel<<<dim3(16,16,4), 256, 0, stream>>>(Wq, Wk, Wv, Wo, Wt);
  gemm128<1>   <<<dim3(32,8,3), 256, 0, stream>>>(qbf, Wt, Qh, nullptr, Vt, qn, kn);
  attn_kernel  <<<dim3(1024), 256, 0, stream>>>(Qh, Kh, Vt, qn, kn, gm, aO);
  gemm128<0>   <<<dim3(32,8,1), 256, 0, stream>>>(aO, Wt + 3*1048576, nullptr, out, nullptr, nullptr, nullptr);
}

// Round 3
// 129.503 us; speedup vs baseline: 1.3682x; 1.1134x over previous
//
#include <hip/hip_runtime.h>
#include <stdint.h>

#define SCALE 0.125f   // 1/sqrt(64)

typedef short s16x8 __attribute__((ext_vector_type(8)));
typedef float f32x4 __attribute__((ext_vector_type(4)));

__device__ __forceinline__ unsigned short f2bf(float x){
  union { float f; unsigned int u; } v; v.f = x;
  unsigned int r = v.u + 0x7fffu + ((v.u >> 16) & 1u);
  return (unsigned short)(r >> 16);
}
__device__ __forceinline__ float bf2f(unsigned short u){
  union { unsigned int u; float f; } v; v.u = ((unsigned int)u) << 16;
  return v.f;
}
__device__ __forceinline__ f32x4 mfma16(s16x8 a, s16x8 b, f32x4 c){
  return __builtin_amdgcn_mfma_f32_16x16x32_bf16(a, b, c, 0, 0, 0);
}
__device__ __forceinline__ void gld_lds16(const void* g, void* l){
  __builtin_amdgcn_global_load_lds(
      (const __attribute__((address_space(1))) unsigned int*)g,
      (__attribute__((address_space(3))) unsigned int*)l, 16, 0, 0);
}
__device__ __forceinline__ unsigned int cvtpk(float lo, float hi){
  unsigned int r;
  asm("v_cvt_pk_bf16_f32 %0, %1, %2" : "=v"(r) : "v"(lo), "v"(hi));
  return r;
}

// ---------------- cast q fp32 -> bf16 (4M elems, 8/thread) ----------------
__global__ __launch_bounds__(256) void cast_kernel(const float* __restrict__ in,
                                                   unsigned short* __restrict__ out){
  int i = blockIdx.x*256 + threadIdx.x;
  const float4* p = (const float4*)in + (size_t)i*2;
  float4 a = p[0], b = p[1];
  unsigned short t[8] = {f2bf(a.x),f2bf(a.y),f2bf(a.z),f2bf(a.w),
                         f2bf(b.x),f2bf(b.y),f2bf(b.z),f2bf(b.w)};
  *(s16x8*)(out + (size_t)i*8) = *(const s16x8*)t;
}

// ---------------- W fp32 [K][N] -> bf16 Wt [N][K] (B^T form) ----------------
__global__ __launch_bounds__(256) void wtrans_kernel(const float* __restrict__ W0,
    const float* __restrict__ W1, const float* __restrict__ W2, const float* __restrict__ W3,
    unsigned short* __restrict__ Wt){
  const float* src = (blockIdx.z==0)?W0:(blockIdx.z==1)?W1:(blockIdx.z==2)?W2:W3;
  unsigned short* dst = Wt + (size_t)blockIdx.z*1048576;
  int k0 = blockIdx.x*64, n0 = blockIdx.y*64;
  __shared__ unsigned short tile[64*72];
  int tid = threadIdx.x;
  int r = tid>>2, c = (tid&3)*16;
  const float* p = src + (size_t)(k0+r)*1024 + n0 + c;
  #pragma unroll
  for (int j=0;j<16;j++) tile[r*72 + c + j] = f2bf(p[j]);
  __syncthreads();
  int n = tid>>2, kc = (tid&3)*16;
  unsigned short o[16];
  #pragma unroll
  for (int j=0;j<16;j++) o[j] = tile[(kc+j)*72 + n];
  *(s16x8*)&dst[(size_t)(n0+n)*1024 + k0 + kc]     = *(const s16x8*)o;
  *(s16x8*)&dst[(size_t)(n0+n)*1024 + k0 + kc + 8] = *(const s16x8*)(o+8);
}

// ---------------- V [bh][2048][64] -> Vt [bh][64][2048] ----------------
__global__ __launch_bounds__(256) void vtrans_kernel(const unsigned short* __restrict__ Vh,
    unsigned short* __restrict__ VtG){
  int bh = blockIdx.y, t0 = blockIdx.x*64;
  __shared__ unsigned short tile[64*72];
  int tid = threadIdx.x;
  #pragma unroll
  for (int p=0;p<2;p++){
    int idx = p*2048 + tid*8;
    int r = idx>>6, c = idx&63;
    *(s16x8*)&tile[r*72 + c] = *(const s16x8*)&Vh[((size_t)bh*2048 + t0 + r)*64 + c];
  }
  __syncthreads();
  #pragma unroll
  for (int p=0;p<2;p++){
    int idx = p*2048 + tid*8;
    int d = idx>>6, c = idx&63;
    unsigned short o[8];
    #pragma unroll
    for (int j=0;j<8;j++) o[j] = tile[(c+j)*72 + d];
    *(s16x8*)&VtG[((size_t)bh*64 + d)*2048 + t0 + c] = *(const s16x8*)o;
  }
}

// ---------------- 128x128xBK64 bf16 GEMM, dbuf, 1 barrier/step ----------------
// 512 threads, 8 waves as 4(m) x 2(n); per wave 32x64 output (acc[2][4]).
// LDS XOR chunk-swizzle (pre-swizzled global src + swizzled ds_read).
// MODE 0: C fp32 -> outF [4096][1024]  (Bt passed already offset to Wo)
// MODE 1: N fused 3072 (z = n>>10): z<2 -> Qh/Kh heads layout + fused norms;
//         z==2 -> Vh heads layout (coalesced; transpose done by vtrans_kernel)
template<int MODE>
__global__ __launch_bounds__(512) void gemm_db(const unsigned short* __restrict__ A,
    const unsigned short* __restrict__ Bt, unsigned short* __restrict__ outH,
    float* __restrict__ outF, float* __restrict__ qn, float* __restrict__ kn){
  __shared__ short As[16384];   // 2 x [128][64]
  __shared__ short Bs[16384];
  int tid = threadIdx.x;
  int w = tid>>6, l = tid&63;
  int lm = l & 15, hi = l >> 4;
  int wr = w>>1, wc = w&1;
  int m0 = blockIdx.x*128, n0 = blockIdx.y*128;

  const unsigned short* Bz;
  int bn0;
  if constexpr (MODE==1){ Bz = Bt + (size_t)(n0>>10)*1048576; bn0 = n0 & 1023; }
  else                  { Bz = Bt; bn0 = n0; }

  f32x4 acc[2][4];
  #pragma unroll
  for (int r=0;r<2;r++)
    #pragma unroll
    for (int c=0;c<4;c++){ f32x4 z = {0.f,0.f,0.f,0.f}; acc[r][c] = z; }

  // staging: per wave 2 issues for A (rows w*16+j*8) and 2 for B; lane: row +=
  // l>>3, source chunk = (l&7) ^ (l>>3)  (XOR involution; LDS dest stays linear)
  int rsub = l>>3, csw = ((l&7) ^ (l>>3))*8;
  const unsigned short* gA = A  + (size_t)(m0  + w*16 + rsub)*1024 + csw;
  const unsigned short* gB = Bz + (size_t)(bn0 + w*16 + rsub)*1024 + csw;
  short* lA = As + w*1024;   // shorts; issue j adds 512
  short* lB = Bs + w*1024;

  // read-side swizzled chunk offsets (shorts): chunk(s) = (s*4+hi) ^ (lm&7)
  int ch0 = ((hi)     ^ (lm&7))*8;
  int ch1 = ((4 + hi) ^ (lm&7))*8;

  // prologue: stage k-tile 0 into buf 0
  gld_lds16(gA,        lA);
  gld_lds16(gA + 8192, lA + 512);
  gld_lds16(gB,        lB);
  gld_lds16(gB + 8192, lB + 512);
  __syncthreads();

  const int NKT = 16;  // 1024 / 64
  int buf = 0;
  for (int kt=0; kt<NKT; ++kt){
    // stage next k-tile into the other buffer (loads stay in flight over compute)
    if (kt+1 < NKT){
      const unsigned short* a = gA + (size_t)(kt+1)*64;
      const unsigned short* b = gB + (size_t)(kt+1)*64;
      short* dA = As + (buf^1)*8192 + w*1024;
      short* dB = Bs + (buf^1)*8192 + w*1024;
      gld_lds16(a,        dA);
      gld_lds16(a + 8192, dA + 512);
      gld_lds16(b,        dB);
      gld_lds16(b + 8192, dB + 512);
    }
    const short* curA = As + buf*8192;
    const short* curB = Bs + buf*8192;
    s16x8 af[2][2], bfv[4][2];
    #pragma unroll
    for (int r=0;r<2;r++){
      int ro = (wr*32 + r*16 + lm)*64;
      af[r][0] = *(const s16x8*)(curA + ro + ch0);
      af[r][1] = *(const s16x8*)(curA + ro + ch1);
    }
    #pragma unroll
    for (int c=0;c<4;c++){
      int ro = (wc*64 + c*16 + lm)*64;
      bfv[c][0] = *(const s16x8*)(curB + ro + ch0);
      bfv[c][1] = *(const s16x8*)(curB + ro + ch1);
    }
    #pragma unroll
    for (int s=0;s<2;s++)
      #pragma unroll
      for (int r=0;r<2;r++)
        #pragma unroll
        for (int c=0;c<4;c++)
          acc[r][c] = mfma16(af[r][s], bfv[c][s], acc[r][c]);
    __syncthreads();   // drains vmcnt(0) AFTER compute: next buf ready, cur buf free
    buf ^= 1;
  }

  if constexpr (MODE==0){
    #pragma unroll
    for (int r=0;r<2;r++)
      #pragma unroll
      for (int c=0;c<4;c++)
        #pragma unroll
        for (int i=0;i<4;i++){
          int m = m0 + wr*32 + r*16 + hi*4 + i;
          int n = n0 + wc*64 + c*16 + lm;
          outF[(size_t)m*1024 + n] = acc[r][c][i];
        }
  } else {
    int z = n0 >> 10;
    unsigned short* oz = outH + (size_t)z*4194304;
    #pragma unroll
    for (int r=0;r<2;r++){
      #pragma unroll
      for (int i=0;i<4;i++){
        int m = m0 + wr*32 + r*16 + hi*4 + i;
        int bq = m >> 11, sq = m & 2047;
        float nrm = 0.f;
        #pragma unroll
        for (int c=0;c<4;c++){
          int nn = (n0 & 1023) + wc*64 + c*16 + lm;
          int hq = nn >> 6, dq = nn & 63;
          int bh = bq*16 + hq;
          unsigned short bv = f2bf(acc[r][c][i]);
          oz[((size_t)bh*2048 + sq)*64 + dq] = bv;
          float vf = bf2f(bv);
          nrm = fmaf(vf, vf, nrm);
        }
        if (z < 2){
          nrm += __shfl_xor(nrm, 1);
          nrm += __shfl_xor(nrm, 2);
          nrm += __shfl_xor(nrm, 4);
          nrm += __shfl_xor(nrm, 8);
          if (lm == 0){
            int hq = ((n0 & 1023) + wc*64) >> 6;
            float* dst = z ? kn : qn;
            dst[(size_t)(bq*16 + hq)*2048 + sq] = nrm;
          }
        }
      }
    }
  }
}

// ---------------- attention ----------------
// out[s] = sum_{t>s} exp(-g*SCALE*max(qn[s]-2*q.k+kn[t],0)) * v[t]
__global__ __launch_bounds__(256) void attn_kernel(const unsigned short* __restrict__ Qh,
    const unsigned short* __restrict__ Kh, const unsigned short* __restrict__ VtG,
    const float* __restrict__ qn, const float* __restrict__ kn,
    const float* __restrict__ gamma, unsigned short* __restrict__ attnO){
  __shared__ short Ks[2][4096];   // [t 64][d 64], chunk-swizzled
  __shared__ short Vs[2][4096];   // [d 64][t 64], chunk-swizzled
  __shared__ short Ps[4][1024];   // per-wave P [m 16][t 64], swizzled

  int bid = blockIdx.x;
  int bh = bid & 31; int b = bh>>4, h = bh&15;
  int rr = bid >> 5;
  int si = (rr&1) ? (31 - (rr>>1)) : (rr>>1);   // heavy/light pairing
  int s0 = si*64;
  int tid = threadIdx.x, w = tid>>6, l = tid&63;
  int lm = l & 15, hi = l >> 4;
  float gs = gamma[h]*SCALE;
  float gs2 = 2.f*gs;

  int sq = s0 + w*16 + lm;
  const unsigned short* qbase = Qh + ((size_t)bh*2048 + sq)*64;
  s16x8 qf0 = *(const s16x8*)(qbase + hi*8);
  s16x8 qf1 = *(const s16x8*)(qbase + 32 + hi*8);
  float qn_r = qn[(size_t)bh*2048 + sq];
  float gq = -gs*qn_r;
  const float* knp = kn + (size_t)bh*2048;

  int chs = ((l&7) ^ (l>>3))*8;
  const unsigned short* kp0 = Kh  + ((size_t)bh*2048 + s0 + w*8 + (l>>3))*64 + chs;
  const unsigned short* vp0 = VtG + ((size_t)bh*64 + w*8 + (l>>3))*2048 + s0 + chs;

  f32x4 accO[4];
  #pragma unroll
  for (int df=0; df<4; df++){ f32x4 zz = {0.f,0.f,0.f,0.f}; accO[df] = zz; }

  gld_lds16(kp0,           &Ks[0][w*512]);
  gld_lds16(kp0 + 32*64,   &Ks[0][w*512 + 2048]);
  gld_lds16(vp0,           &Vs[0][w*512]);
  gld_lds16(vp0 + 32*2048, &Vs[0][w*512 + 2048]);
  __syncthreads();

  int swl = (lm & 7) << 4;
  int cur = 0;
  for (int t0 = s0; t0 < 2048; t0 += 64, cur ^= 1){
    int nxt = t0 + 64;
    if (nxt < 2048){
      int dt = nxt - s0;
      const unsigned short* kp = kp0 + (size_t)dt*64;
      const unsigned short* vp = vp0 + dt;
      gld_lds16(kp,           &Ks[cur^1][w*512]);
      gld_lds16(kp + 32*64,   &Ks[cur^1][w*512 + 2048]);
      gld_lds16(vp,           &Vs[cur^1][w*512]);
      gld_lds16(vp + 32*2048, &Vs[cur^1][w*512 + 2048]);
    }
    const char* kbase = (const char*)&Ks[cur][0];
    const char* vbase = (const char*)&Vs[cur][0];
    char* pbase = (char*)&Ps[w][0];

    #pragma unroll
    for (int tf=0; tf<4; tf++){
      int ro = (tf*16 + lm)*128;
      s16x8 ka = *(const s16x8*)(kbase + ro + ((hi*16) ^ swl));
      s16x8 kb = *(const s16x8*)(kbase + ro + ((64 + hi*16) ^ swl));
      f32x4 sc = {0.f,0.f,0.f,0.f};
      sc = mfma16(ka, qf0, sc);
      sc = mfma16(kb, qf1, sc);
      float4 knv = *(const float4*)(knp + t0 + tf*16 + hi*4);
      float p0, p1, p2, p3;
      {
        int tbase = t0 + tf*16 + hi*4;
        float a0 = fminf(fmaf(gs2, sc[0], fmaf(-gs, knv.x, gq)), 0.f);
        float a1 = fminf(fmaf(gs2, sc[1], fmaf(-gs, knv.y, gq)), 0.f);
        float a2 = fminf(fmaf(gs2, sc[2], fmaf(-gs, knv.z, gq)), 0.f);
        float a3 = fminf(fmaf(gs2, sc[3], fmaf(-gs, knv.w, gq)), 0.f);
        p0 = (tbase + 0 > sq) ? __expf(a0) : 0.f;
        p1 = (tbase + 1 > sq) ? __expf(a1) : 0.f;
        p2 = (tbase + 2 > sq) ? __expf(a2) : 0.f;
        p3 = (tbase + 3 > sq) ? __expf(a3) : 0.f;
      }
      unsigned int pk0 = cvtpk(p0, p1);
      unsigned int pk1 = cvtpk(p2, p3);
      int po = lm*128 + (((tf*32 + hi*8) ^ swl));
      *(unsigned int*)(pbase + po)     = pk0;
      *(unsigned int*)(pbase + po + 4) = pk1;
    }

    #pragma unroll
    for (int kf=0; kf<2; kf++){
      s16x8 pa = *(const s16x8*)(pbase + lm*128 + ((kf*64 + hi*16) ^ swl));
      #pragma unroll
      for (int df=0; df<4; df++){
        int vo = (df*16 + lm)*128 + ((kf*64 + hi*16) ^ swl);
        s16x8 vb = *(const s16x8*)(vbase + vo);
        accO[df] = mfma16(pa, vb, accO[df]);
      }
    }
    __syncthreads();
  }

  #pragma unroll
  for (int df=0; df<4; df++)
    #pragma unroll
    for (int i=0; i<4; i++){
      int s = s0 + w*16 + hi*4 + i;
      attnO[((size_t)b*2048 + s)*1024 + h*64 + df*16 + lm] = f2bf(accO[df][i]);
    }
}

extern "C" void kernel_launch(void* const* d_in, const int* in_sizes, int n_in,
                              void* d_out, int out_size, void* d_ws, size_t ws_size,
                              hipStream_t stream){
  const float* q  = (const float*)d_in[0];
  const float* Wq = (const float*)d_in[1];
  const float* Wk = (const float*)d_in[2];
  const float* Wv = (const float*)d_in[3];
  const float* Wo = (const float*)d_in[4];
  const float* gm = (const float*)d_in[5];
  float* out = (float*)d_out;

  unsigned short* qbf = (unsigned short*)d_ws;  // 4096x1024 bf16
  unsigned short* Wt  = qbf + 4194304;          // 4 x [1024][1024] bf16 (B^T form)
  unsigned short* Qh  = Wt  + 4194304;          // [bh][2048][64]
  unsigned short* Kh  = Qh  + 4194304;
  unsigned short* Vh  = Kh  + 4194304;
  unsigned short* Vt  = Vh  + 4194304;          // [bh][64][2048]
  unsigned short* aO  = Vt  + 4194304;          // [4096][1024] bf16
  float* qn = (float*)(aO + 4194304);           // [bh*2048]
  float* kn = qn + 65536;

  cast_kernel  <<<2048, 256, 0, stream>>>(q, qbf);
  wtrans_kernel<<<dim3(16,16,4), 256, 0, stream>>>(Wq, Wk, Wv, Wo, Wt);
  gemm_db<1>   <<<dim3(32,24), 512, 0, stream>>>(qbf, Wt, Qh, nullptr, qn, kn);
  vtrans_kernel<<<dim3(32,32), 256, 0, stream>>>(Vh, Vt);
  attn_kernel  <<<dim3(1024), 256, 0, stream>>>(Qh, Kh, Vt, qn, kn, gm, aO);
  gemm_db<0>   <<<dim3(32,8), 512, 0, stream>>>(aO, Wt + 3*1048576, nullptr, out, nullptr, nullptr);
}

// Round 4
// 114.127 us; speedup vs baseline: 1.5526x; 1.1347x over previous
//
#include <hip/hip_runtime.h>
#include <stdint.h>

#define SCALE 0.125f   // 1/sqrt(64)
#define GSL_C 0.180336880111f   // SCALE * log2(e)

typedef short s16x8 __attribute__((ext_vector_type(8)));
typedef float f32x4 __attribute__((ext_vector_type(4)));

__device__ __forceinline__ unsigned short f2bf(float x){
  union { float f; unsigned int u; } v; v.f = x;
  unsigned int r = v.u + 0x7fffu + ((v.u >> 16) & 1u);
  return (unsigned short)(r >> 16);
}
__device__ __forceinline__ float bf2f(unsigned short u){
  union { unsigned int u; float f; } v; v.u = ((unsigned int)u) << 16;
  return v.f;
}
__device__ __forceinline__ f32x4 mfma16(s16x8 a, s16x8 b, f32x4 c){
  return __builtin_amdgcn_mfma_f32_16x16x32_bf16(a, b, c, 0, 0, 0);
}
__device__ __forceinline__ void gld_lds16(const void* g, void* l){
  __builtin_amdgcn_global_load_lds(
      (const __attribute__((address_space(1))) unsigned int*)g,
      (__attribute__((address_space(3))) unsigned int*)l, 16, 0, 0);
}
__device__ __forceinline__ unsigned int cvtpk(float lo, float hi){
  unsigned int r;
  asm("v_cvt_pk_bf16_f32 %0, %1, %2" : "=v"(r) : "v"(lo), "v"(hi));
  return r;
}

// ---------------- cast q fp32 -> bf16 (4M elems, 8/thread) ----------------
__global__ __launch_bounds__(256) void cast_kernel(const float* __restrict__ in,
                                                   unsigned short* __restrict__ out){
  int i = blockIdx.x*256 + threadIdx.x;
  const float4* p = (const float4*)in + (size_t)i*2;
  float4 a = p[0], b = p[1];
  unsigned short t[8] = {f2bf(a.x),f2bf(a.y),f2bf(a.z),f2bf(a.w),
                         f2bf(b.x),f2bf(b.y),f2bf(b.z),f2bf(b.w)};
  *(s16x8*)(out + (size_t)i*8) = *(const s16x8*)t;
}

// ---------------- W fp32 [K][N] -> bf16 Wt [N][K] (B^T form) ----------------
__global__ __launch_bounds__(256) void wtrans_kernel(const float* __restrict__ W0,
    const float* __restrict__ W1, const float* __restrict__ W2, const float* __restrict__ W3,
    unsigned short* __restrict__ Wt){
  const float* src = (blockIdx.z==0)?W0:(blockIdx.z==1)?W1:(blockIdx.z==2)?W2:W3;
  unsigned short* dst = Wt + (size_t)blockIdx.z*1048576;
  int k0 = blockIdx.x*64, n0 = blockIdx.y*64;
  __shared__ unsigned short tile[64*72];
  int tid = threadIdx.x;
  int r = tid>>2, c = (tid&3)*16;
  const float* p = src + (size_t)(k0+r)*1024 + n0 + c;
  #pragma unroll
  for (int j=0;j<16;j++) tile[r*72 + c + j] = f2bf(p[j]);
  __syncthreads();
  int n = tid>>2, kc = (tid&3)*16;
  unsigned short o[16];
  #pragma unroll
  for (int j=0;j<16;j++) o[j] = tile[(kc+j)*72 + n];
  *(s16x8*)&dst[(size_t)(n0+n)*1024 + k0 + kc]     = *(const s16x8*)o;
  *(s16x8*)&dst[(size_t)(n0+n)*1024 + k0 + kc + 8] = *(const s16x8*)(o+8);
}

// ---------------- V [bh][2048][64] -> Vt [bh][64][2048] ----------------
__global__ __launch_bounds__(256) void vtrans_kernel(const unsigned short* __restrict__ Vh,
    unsigned short* __restrict__ VtG){
  int bh = blockIdx.y, t0 = blockIdx.x*64;
  __shared__ unsigned short tile[64*72];
  int tid = threadIdx.x;
  #pragma unroll
  for (int p=0;p<2;p++){
    int idx = p*2048 + tid*8;
    int r = idx>>6, c = idx&63;
    *(s16x8*)&tile[r*72 + c] = *(const s16x8*)&Vh[((size_t)bh*2048 + t0 + r)*64 + c];
  }
  __syncthreads();
  #pragma unroll
  for (int p=0;p<2;p++){
    int idx = p*2048 + tid*8;
    int d = idx>>6, c = idx&63;
    unsigned short o[8];
    #pragma unroll
    for (int j=0;j<8;j++) o[j] = tile[(c+j)*72 + d];
    *(s16x8*)&VtG[((size_t)bh*64 + d)*2048 + t0 + c] = *(const s16x8*)o;
  }
}

// ---------------- 128x128xBK64 bf16 GEMM, dbuf, 1 barrier/step ----------------
// MODE 0: C fp32 -> outF [4096][1024]
// MODE 1: N fused 3072: z<2 -> Qh/Kh heads layout + fused PRESCALED norms
//         (qn' = gamma*SCALE*log2e * ||q||^2); z==2 -> Vh heads layout
template<int MODE>
__global__ __launch_bounds__(512) void gemm_db(const unsigned short* __restrict__ A,
    const unsigned short* __restrict__ Bt, unsigned short* __restrict__ outH,
    float* __restrict__ outF, float* __restrict__ qn, float* __restrict__ kn,
    const float* __restrict__ gamma){
  __shared__ short As[16384];   // 2 x [128][64]
  __shared__ short Bs[16384];
  int tid = threadIdx.x;
  int w = tid>>6, l = tid&63;
  int lm = l & 15, hi = l >> 4;
  int wr = w>>1, wc = w&1;
  int m0 = blockIdx.x*128, n0 = blockIdx.y*128;

  const unsigned short* Bz;
  int bn0;
  if constexpr (MODE==1){ Bz = Bt + (size_t)(n0>>10)*1048576; bn0 = n0 & 1023; }
  else                  { Bz = Bt; bn0 = n0; }

  f32x4 acc[2][4];
  #pragma unroll
  for (int r=0;r<2;r++)
    #pragma unroll
    for (int c=0;c<4;c++){ f32x4 z = {0.f,0.f,0.f,0.f}; acc[r][c] = z; }

  int rsub = l>>3, csw = ((l&7) ^ (l>>3))*8;
  const unsigned short* gA = A  + (size_t)(m0  + w*16 + rsub)*1024 + csw;
  const unsigned short* gB = Bz + (size_t)(bn0 + w*16 + rsub)*1024 + csw;
  short* lA = As + w*1024;
  short* lB = Bs + w*1024;

  int ch0 = ((hi)     ^ (lm&7))*8;
  int ch1 = ((4 + hi) ^ (lm&7))*8;

  gld_lds16(gA,        lA);
  gld_lds16(gA + 8192, lA + 512);
  gld_lds16(gB,        lB);
  gld_lds16(gB + 8192, lB + 512);
  __syncthreads();

  const int NKT = 16;
  int buf = 0;
  for (int kt=0; kt<NKT; ++kt){
    if (kt+1 < NKT){
      const unsigned short* a = gA + (size_t)(kt+1)*64;
      const unsigned short* b = gB + (size_t)(kt+1)*64;
      short* dA = As + (buf^1)*8192 + w*1024;
      short* dB = Bs + (buf^1)*8192 + w*1024;
      gld_lds16(a,        dA);
      gld_lds16(a + 8192, dA + 512);
      gld_lds16(b,        dB);
      gld_lds16(b + 8192, dB + 512);
    }
    const short* curA = As + buf*8192;
    const short* curB = Bs + buf*8192;
    s16x8 af[2][2], bfv[4][2];
    #pragma unroll
    for (int r=0;r<2;r++){
      int ro = (wr*32 + r*16 + lm)*64;
      af[r][0] = *(const s16x8*)(curA + ro + ch0);
      af[r][1] = *(const s16x8*)(curA + ro + ch1);
    }
    #pragma unroll
    for (int c=0;c<4;c++){
      int ro = (wc*64 + c*16 + lm)*64;
      bfv[c][0] = *(const s16x8*)(curB + ro + ch0);
      bfv[c][1] = *(const s16x8*)(curB + ro + ch1);
    }
    __builtin_amdgcn_s_setprio(1);
    #pragma unroll
    for (int s=0;s<2;s++)
      #pragma unroll
      for (int r=0;r<2;r++)
        #pragma unroll
        for (int c=0;c<4;c++)
          acc[r][c] = mfma16(af[r][s], bfv[c][s], acc[r][c]);
    __builtin_amdgcn_s_setprio(0);
    __syncthreads();
    buf ^= 1;
  }

  if constexpr (MODE==0){
    #pragma unroll
    for (int r=0;r<2;r++)
      #pragma unroll
      for (int c=0;c<4;c++)
        #pragma unroll
        for (int i=0;i<4;i++){
          int m = m0 + wr*32 + r*16 + hi*4 + i;
          int n = n0 + wc*64 + c*16 + lm;
          outF[(size_t)m*1024 + n] = acc[r][c][i];
        }
  } else {
    int z = n0 >> 10;
    unsigned short* oz = outH + (size_t)z*4194304;
    #pragma unroll
    for (int r=0;r<2;r++){
      #pragma unroll
      for (int i=0;i<4;i++){
        int m = m0 + wr*32 + r*16 + hi*4 + i;
        int bq = m >> 11, sq = m & 2047;
        float nrm = 0.f;
        #pragma unroll
        for (int c=0;c<4;c++){
          int nn = (n0 & 1023) + wc*64 + c*16 + lm;
          int hq = nn >> 6, dq = nn & 63;
          int bh = bq*16 + hq;
          unsigned short bv = f2bf(acc[r][c][i]);
          oz[((size_t)bh*2048 + sq)*64 + dq] = bv;
          float vf = bf2f(bv);
          nrm = fmaf(vf, vf, nrm);
        }
        if (z < 2){
          nrm += __shfl_xor(nrm, 1);
          nrm += __shfl_xor(nrm, 2);
          nrm += __shfl_xor(nrm, 4);
          nrm += __shfl_xor(nrm, 8);
          if (lm == 0){
            int hq = ((n0 & 1023) + wc*64) >> 6;
            float gsl_h = gamma[hq] * GSL_C;
            float* dst = z ? kn : qn;
            dst[(size_t)(bq*16 + hq)*2048 + sq] = nrm * gsl_h;
          }
        }
      }
    }
  }
}

// ---------------- attention ----------------
// p = exp2( min( 2*gsl*qk - qn' - kn', 0 ) ), qn'/kn' prescaled by gsl
__global__ __launch_bounds__(256) void attn_kernel(const unsigned short* __restrict__ Qh,
    const unsigned short* __restrict__ Kh, const unsigned short* __restrict__ VtG,
    const float* __restrict__ qn, const float* __restrict__ kn,
    const float* __restrict__ gamma, unsigned short* __restrict__ attnO){
  __shared__ short Ks[2][4096];   // [t 64][d 64], chunk-swizzled
  __shared__ short Vs[2][4096];   // [d 64][t 64], chunk-swizzled
  __shared__ short Ps[4][1024];   // per-wave P [m 16][t 64], swizzled

  int bid = blockIdx.x;
  int bh = bid & 31; int b = bh>>4, h = bh&15;
  int rr = bid >> 5;
  // CU-balanced si map: CU hosts rr quadruple {r8, r8+8, r8+16, r8+24} ->
  // si {r8, 31-r8, 8+r8, 23-r8}, tile counts sum to 66 for every r8.
  int g = rr >> 3, r8 = rr & 7;
  int si = (g==0) ? r8 : (g==1) ? (31-r8) : (g==2) ? (8+r8) : (23-r8);
  int s0 = si*64;
  int tid = threadIdx.x, w = tid>>6, l = tid&63;
  int lm = l & 15, hi = l >> 4;
  float gs2l = 2.f * gamma[h] * GSL_C;

  int sq = s0 + w*16 + lm;
  const unsigned short* qbase = Qh + ((size_t)bh*2048 + sq)*64;
  s16x8 qf0 = *(const s16x8*)(qbase + hi*8);
  s16x8 qf1 = *(const s16x8*)(qbase + 32 + hi*8);
  float gq = -qn[(size_t)bh*2048 + sq];   // prescaled
  const float* knp = kn + (size_t)bh*2048;

  int chs = ((l&7) ^ (l>>3))*8;
  const unsigned short* kp0 = Kh  + ((size_t)bh*2048 + s0 + w*8 + (l>>3))*64 + chs;
  const unsigned short* vp0 = VtG + ((size_t)bh*64 + w*8 + (l>>3))*2048 + s0 + chs;

  f32x4 accO[4];
  #pragma unroll
  for (int df=0; df<4; df++){ f32x4 zz = {0.f,0.f,0.f,0.f}; accO[df] = zz; }

  gld_lds16(kp0,           &Ks[0][w*512]);
  gld_lds16(kp0 + 32*64,   &Ks[0][w*512 + 2048]);
  gld_lds16(vp0,           &Vs[0][w*512]);
  gld_lds16(vp0 + 32*2048, &Vs[0][w*512 + 2048]);
  __syncthreads();

  int swl = (lm & 7) << 4;
  int cur = 0;
  for (int t0 = s0; t0 < 2048; t0 += 64, cur ^= 1){
    int nxt = t0 + 64;
    if (nxt < 2048){
      int dt = nxt - s0;
      const unsigned short* kp = kp0 + (size_t)dt*64;
      const unsigned short* vp = vp0 + dt;
      gld_lds16(kp,           &Ks[cur^1][w*512]);
      gld_lds16(kp + 32*64,   &Ks[cur^1][w*512 + 2048]);
      gld_lds16(vp,           &Vs[cur^1][w*512]);
      gld_lds16(vp + 32*2048, &Vs[cur^1][w*512 + 2048]);
    }
    const char* kbase = (const char*)&Ks[cur][0];
    const char* vbase = (const char*)&Vs[cur][0];
    char* pbase = (char*)&Ps[w][0];

    #pragma unroll
    for (int tf=0; tf<4; tf++){
      int ro = (tf*16 + lm)*128;
      s16x8 ka = *(const s16x8*)(kbase + ro + ((hi*16) ^ swl));
      s16x8 kb = *(const s16x8*)(kbase + ro + ((64 + hi*16) ^ swl));
      f32x4 sc = {0.f,0.f,0.f,0.f};
      __builtin_amdgcn_s_setprio(1);
      sc = mfma16(ka, qf0, sc);
      sc = mfma16(kb, qf1, sc);
      __builtin_amdgcn_s_setprio(0);
      float4 knv = *(const float4*)(knp + t0 + tf*16 + hi*4);
      float a0 = fminf(fmaf(gs2l, sc[0], gq - knv.x), 0.f);
      float a1 = fminf(fmaf(gs2l, sc[1], gq - knv.y), 0.f);
      float a2 = fminf(fmaf(gs2l, sc[2], gq - knv.z), 0.f);
      float a3 = fminf(fmaf(gs2l, sc[3], gq - knv.w), 0.f);
      float e0 = __builtin_amdgcn_exp2f(a0);
      float e1 = __builtin_amdgcn_exp2f(a1);
      float e2 = __builtin_amdgcn_exp2f(a2);
      float e3 = __builtin_amdgcn_exp2f(a3);
      if (t0 == s0){   // only the diagonal tile needs the strict-upper mask
        int tbase = t0 + tf*16 + hi*4;
        e0 = (tbase + 0 > sq) ? e0 : 0.f;
        e1 = (tbase + 1 > sq) ? e1 : 0.f;
        e2 = (tbase + 2 > sq) ? e2 : 0.f;
        e3 = (tbase + 3 > sq) ? e3 : 0.f;
      }
      uint2 pk;
      pk.x = cvtpk(e0, e1);
      pk.y = cvtpk(e2, e3);
      int po = lm*128 + (((tf*32 + hi*8) ^ swl));
      *(uint2*)(pbase + po) = pk;
    }

    __builtin_amdgcn_s_setprio(1);
    #pragma unroll
    for (int kf=0; kf<2; kf++){
      s16x8 pa = *(const s16x8*)(pbase + lm*128 + ((kf*64 + hi*16) ^ swl));
      #pragma unroll
      for (int df=0; df<4; df++){
        int vo = (df*16 + lm)*128 + ((kf*64 + hi*16) ^ swl);
        s16x8 vb = *(const s16x8*)(vbase + vo);
        accO[df] = mfma16(pa, vb, accO[df]);
      }
    }
    __builtin_amdgcn_s_setprio(0);
    __syncthreads();
  }

  #pragma unroll
  for (int df=0; df<4; df++)
    #pragma unroll
    for (int i=0; i<4; i++){
      int s = s0 + w*16 + hi*4 + i;
      attnO[((size_t)b*2048 + s)*1024 + h*64 + df*16 + lm] = f2bf(accO[df][i]);
    }
}

extern "C" void kernel_launch(void* const* d_in, const int* in_sizes, int n_in,
                              void* d_out, int out_size, void* d_ws, size_t ws_size,
                              hipStream_t stream){
  const float* q  = (const float*)d_in[0];
  const float* Wq = (const float*)d_in[1];
  const float* Wk = (const float*)d_in[2];
  const float* Wv = (const float*)d_in[3];
  const float* Wo = (const float*)d_in[4];
  const float* gm = (const float*)d_in[5];
  float* out = (float*)d_out;

  unsigned short* qbf = (unsigned short*)d_ws;  // 4096x1024 bf16
  unsigned short* Wt  = qbf + 4194304;          // 4 x [1024][1024] bf16 (B^T form)
  unsigned short* Qh  = Wt  + 4194304;          // [bh][2048][64]
  unsigned short* Kh  = Qh  + 4194304;
  unsigned short* Vh  = Kh  + 4194304;
  unsigned short* Vt  = Vh  + 4194304;          // [bh][64][2048]
  unsigned short* aO  = Vt  + 4194304;          // [4096][1024] bf16
  float* qn = (float*)(aO + 4194304);           // [bh*2048], prescaled
  float* kn = qn + 65536;

  cast_kernel  <<<2048, 256, 0, stream>>>(q, qbf);
  wtrans_kernel<<<dim3(16,16,4), 256, 0, stream>>>(Wq, Wk, Wv, Wo, Wt);
  gemm_db<1>   <<<dim3(32,24), 512, 0, stream>>>(qbf, Wt, Qh, nullptr, qn, kn, gm);
  vtrans_kernel<<<dim3(32,32), 256, 0, stream>>>(Vh, Vt);
  attn_kernel  <<<dim3(1024), 256, 0, stream>>>(Qh, Kh, Vt, qn, kn, gm, aO);
  gemm_db<0>   <<<dim3(32,8), 512, 0, stream>>>(aO, Wt + 3*1048576, nullptr, out, nullptr, nullptr, nullptr);
}